// Round 10
// baseline (192.990 us; speedup 1.0000x reference)
//
#include <hip/hip_runtime.h>
#include <float.h>

typedef _Float16 half8 __attribute__((ext_vector_type(8)));
typedef _Float16 half4 __attribute__((ext_vector_type(4)));
typedef float    f32x4 __attribute__((ext_vector_type(4)));

// Problem constants
constexpr int N_TOK = 65536;        // 16*64*64 tokens
constexpr int D     = 64;           // embedding dim
constexpr int K     = 2048;         // codebook size
constexpr int SPLIT = 4;            // code-range split
constexpr int KO    = K / SPLIT;    // 512 codes per split
constexpr int TILE_C = 64;          // codes per LDS tile (16.3 KB hi+lo+hn)
constexpr int TOK_PER_BLK = 256;    // 4 waves x 64 tokens (vq_dist)
constexpr int NBLK_EPI = N_TOK * 16 / 256;   // 4096 epilogue blocks
constexpr float EPS_RESCORE = 2e-3f; // >> worst-case MFMA-path dist error (~1e-4)

// Output layout (all float32, concatenated in reference return order)
constexpr size_t QN       = (size_t)N_TOK * D;
constexpr size_t SCAL_OFF = QN;
constexpr size_t IDX_OFF  = QN + 5;
constexpr size_t PROB_OFF = IDX_OFF + N_TOK;

// Workspace layout (bytes), total ~2.7 MB
constexpr size_t WS_HNORM = 0;                                    // [K] f32  0.5*||c||^2
constexpr size_t WS_COUNT = 8192;                                 // [K] u32
constexpr size_t WS_KAND  = 16384;                                // [N][SPLIT] u64 keys (2 MB)
constexpr size_t WS_BSUM  = WS_KAND + (size_t)N_TOK * SPLIT * 8;  // [4096] double
constexpr size_t WS_EHI   = WS_BSUM + (size_t)NBLK_EPI * 8;       // [K*D] f16
constexpr size_t WS_ELO   = WS_EHI + (size_t)K * D * 2;           // [K*D] f16

__device__ inline unsigned long long pack_key(float d, int k) {
    unsigned u = __float_as_uint(d);
    u = (u & 0x80000000u) ? ~u : (u | 0x80000000u);   // monotone float->uint
    return ((unsigned long long)u << 32) | (unsigned)k;
}

__device__ inline float unpack_dist(unsigned long long key) {
    unsigned u = (unsigned)(key >> 32);
    u = (u & 0x80000000u) ? (u & 0x7FFFFFFFu) : ~u;   // inverse monotone map
    return __uint_as_float(u);
}

__device__ inline unsigned long long shfl_xor_u64_w16(unsigned long long v, int m) {
    int lo = __shfl_xor((int)(unsigned)v, m, 16);
    int hi = __shfl_xor((int)(unsigned)(v >> 32), m, 16);
    return ((unsigned long long)(unsigned)hi << 32) | (unsigned)lo;
}

// 16 lanes per codebook row: coalesced convert + hnorm; zero counts/blocksums.
__global__ __launch_bounds__(256) void vq_init(const float* __restrict__ emb,
                                               float* __restrict__ hnorm,
                                               unsigned* __restrict__ counts,
                                               double* __restrict__ blocksums,
                                               _Float16* __restrict__ ehi,
                                               _Float16* __restrict__ elo) {
    int g = blockIdx.x * 256 + threadIdx.x;   // 0..32767
    int r = g >> 4;                           // codebook row
    int j = g & 15;                           // float4 within row
    float4 v = ((const float4*)emb)[r * 16 + j];
    float vv[4] = {v.x, v.y, v.z, v.w};
    half4 h, l;
#pragma unroll
    for (int i = 0; i < 4; ++i) {
        _Float16 hh = (_Float16)vv[i];
        h[i] = hh;
        l[i] = (_Float16)(vv[i] - (float)hh);
    }
    ((half4*)ehi)[r * 16 + j] = h;
    ((half4*)elo)[r * 16 + j] = l;

    float p = v.x * v.x + v.y * v.y + v.z * v.z + v.w * v.w;
#pragma unroll
    for (int off = 1; off < 16; off <<= 1) p += __shfl_xor(p, off, 16);
    if (j == 0) hnorm[r] = 0.5f * p;
    if (g < K) counts[g] = 0u;
    if (g < NBLK_EPI) blocksums[g] = 0.0;
}

// MFMA pruning pass. SPLIT=4 (x read 4x not 8x), TILE_C=64 (half the barrier
// drains per code). LDS fragment-major + XOR swizzle (2-way max = free).
// Math identical to r6/r8 (acc1 = hh chain, acc2 = corrections; hn at end).
// Packed (dist,k) u64 per (token,split).
__global__ __launch_bounds__(256) void vq_dist(const float* __restrict__ x,
                                               const float* __restrict__ hnorm,
                                               const _Float16* __restrict__ ehi,
                                               const _Float16* __restrict__ elo,
                                               unsigned long long* __restrict__ kand) {
    __shared__ _Float16 lds_hi[TILE_C * D];   // 8 KB
    __shared__ _Float16 lds_lo[TILE_C * D];   // 8 KB
    __shared__ float    lds_hn[TILE_C];

    const int tid  = threadIdx.x;
    const int lane = tid & 63;
    const int wav  = tid >> 6;
    const int s    = blockIdx.x >> 8;       // split-outer (0..3)
    const int tb   = blockIdx.x & 255;
    const int Tw   = tb * TOK_PER_BLK + wav * 64;
    const int m16  = lane & 15;             // A row (token) / B col (code)
    const int g    = lane >> 4;             // k-chunk group (0..3)
    const int ko   = g * 8;

    // A fragments: 4 a-tiles x 2 k-chunks, negated, hi/lo fp16 split
    half8 axh[4][2], axl[4][2];
#pragma unroll
    for (int a = 0; a < 4; ++a) {
        const float* xr = x + (size_t)(Tw + 16 * a + m16) * D;
#pragma unroll
        for (int c = 0; c < 2; ++c) {
            const float4* p4 = (const float4*)(xr + 32 * c + ko);
            float4 q0 = p4[0], q1 = p4[1];
            float v[8] = {q0.x, q0.y, q0.z, q0.w, q1.x, q1.y, q1.z, q1.w};
            half8 h, l;
#pragma unroll
            for (int j = 0; j < 8; ++j) {
                float nv = -v[j];
                _Float16 hh = (_Float16)nv;
                h[j] = hh;
                l[j] = (_Float16)(nv - (float)hh);
            }
            axh[a][c] = h; axl[a][c] = l;
        }
    }

    float best_d[4][4];
    int   best_k[4][4];
#pragma unroll
    for (int a = 0; a < 4; ++a)
#pragma unroll
        for (int r = 0; r < 4; ++r) { best_d[a][r] = FLT_MAX; best_k[a][r] = 0; }

    const int sc = tid & 7;                 // staging chunk
    const int kobase = s * KO;
    for (int tile = 0; tile < KO / TILE_C; ++tile) {
        const int kbase = kobase + tile * TILE_C;
        __syncthreads();   // previous tile's readers done
#pragma unroll
        for (int it = 0; it < 2; ++it) {
            const int row  = (tid >> 3) + it * 32;
            const int slot = (sc * TILE_C + (row ^ sc)) * 8;
            *(half8*)(lds_hi + slot) = *(const half8*)(ehi + (size_t)(kbase + row) * D + sc * 8);
            *(half8*)(lds_lo + slot) = *(const half8*)(elo + (size_t)(kbase + row) * D + sc * 8);
        }
        if (tid < TILE_C) lds_hn[tid] = hnorm[kbase + tid];
        __syncthreads();

#pragma unroll
        for (int st = 0; st < 4; ++st) {
            const int cl = st * 16 + m16;
            const int s0 = (g * TILE_C + (cl ^ g)) * 8;
            const int s1 = ((4 + g) * TILE_C + (cl ^ (4 + g))) * 8;
            half8 bh0 = *(const half8*)(lds_hi + s0);
            half8 bh1 = *(const half8*)(lds_hi + s1);
            half8 bl0 = *(const half8*)(lds_lo + s0);
            half8 bl1 = *(const half8*)(lds_lo + s1);
            const float hn = lds_hn[cl];
            const int code = kbase + cl;
#pragma unroll
            for (int a = 0; a < 4; ++a) {
                f32x4 acc1 = {0.f, 0.f, 0.f, 0.f};   // hh terms (|.|~8)
                f32x4 acc2 = {0.f, 0.f, 0.f, 0.f};   // corrections (|.|~4e-3)
                acc1 = __builtin_amdgcn_mfma_f32_16x16x32_f16(axh[a][0], bh0, acc1, 0, 0, 0);
                acc1 = __builtin_amdgcn_mfma_f32_16x16x32_f16(axh[a][1], bh1, acc1, 0, 0, 0);
                acc2 = __builtin_amdgcn_mfma_f32_16x16x32_f16(axl[a][0], bh0, acc2, 0, 0, 0);
                acc2 = __builtin_amdgcn_mfma_f32_16x16x32_f16(axl[a][1], bh1, acc2, 0, 0, 0);
                acc2 = __builtin_amdgcn_mfma_f32_16x16x32_f16(axh[a][0], bl0, acc2, 0, 0, 0);
                acc2 = __builtin_amdgcn_mfma_f32_16x16x32_f16(axh[a][1], bl1, acc2, 0, 0, 0);
                acc2 = __builtin_amdgcn_mfma_f32_16x16x32_f16(axl[a][0], bl0, acc2, 0, 0, 0);
                acc2 = __builtin_amdgcn_mfma_f32_16x16x32_f16(axl[a][1], bl1, acc2, 0, 0, 0);
#pragma unroll
                for (int r = 0; r < 4; ++r) {
                    float d = hn + (acc1[r] + acc2[r]);   // argmin-equiv dist
                    if (d < best_d[a][r]) { best_d[a][r] = d; best_k[a][r] = code; }
                }
            }
        }
    }

    // reduce over the 16 code-columns; u64 key min => smaller dist, tie -> smaller k
#pragma unroll
    for (int a = 0; a < 4; ++a)
#pragma unroll
        for (int r = 0; r < 4; ++r) {
            unsigned long long key = pack_key(best_d[a][r], best_k[a][r]);
#pragma unroll
            for (int off = 8; off; off >>= 1) {
                unsigned long long o = shfl_xor_u64_w16(key, off);
                if (o < key) key = o;
            }
            if (m16 == 0) {
                int token = Tw + 16 * a + g * 4 + r;
                kand[(size_t)token * SPLIT + s] = key;
            }
        }
}

// 16 lanes per token, everything coalesced. u64-min over the 4 split keys
// (lane j holds key of split j&3; off=1,2 xor-reduce covers the 4-lane group
// which holds each split exactly once -> cnt = #contender splits).
// cnt>1 -> exact fp32 rescore with coalesced 16-lane row reads + shfl-dot
// (ascending k, strict < = first occurrence). Then quantize/write/sumsq/hist.
__global__ __launch_bounds__(256) void vq_epilogue(const float* __restrict__ x,
                                                   const float* __restrict__ emb,
                                                   const float* __restrict__ hnorm,
                                                   const unsigned long long* __restrict__ kand,
                                                   unsigned* __restrict__ counts,
                                                   double* __restrict__ blocksums,
                                                   float* __restrict__ out) {
    const int gidx = blockIdx.x * 256 + threadIdx.x;
    const int t = gidx >> 4;
    const int j = gidx & 15;

    const unsigned long long mykey = kand[(size_t)t * SPLIT + (j & 3)];
    unsigned long long kmin = mykey;
#pragma unroll
    for (int off = 1; off < 4; off <<= 1) {   // 4-lane xor group = all 4 splits
        unsigned long long o = shfl_xor_u64_w16(kmin, off);
        if (o < kmin) kmin = o;
    }
    int bk = (int)(unsigned)(kmin & 0xFFFFFFFFu);
    const float fmin = unpack_dist(kmin);

    const float4 xj = ((const float4*)x)[t * 16 + j];

    // contender flags: each split appears exactly once in the 4-lane xor group
    const float dj = unpack_dist(mykey);
    int flag = (dj <= fmin + EPS_RESCORE) ? 1 : 0;
    int cnt = flag;
#pragma unroll
    for (int off = 1; off < 4; off <<= 1) cnt += __shfl_xor(cnt, off, 16);

    if (cnt > 1) {   // >1 contender split: exact fp32 rescore (group-uniform branch)
        float best = FLT_MAX;
#pragma unroll
        for (int s = 0; s < SPLIT; ++s) {    // ascending k across splits
            int fs = __shfl(flag, s, 16);
            int ks = __shfl((int)(unsigned)(mykey & 0xFFFFFFFFu), s, 16);
            if (fs) {
                float4 c = ((const float4*)emb)[ks * 16 + j];
                float p = c.x * xj.x + c.y * xj.y + c.z * xj.z + c.w * xj.w;
#pragma unroll
                for (int off = 1; off < 16; off <<= 1) p += __shfl_xor(p, off, 16);
                float hd = hnorm[ks] - p;
                if (hd < best) { best = hd; bk = ks; }
            }
        }
    }

    if (j == 0) {
        out[IDX_OFF + t] = (float)bk;
        atomicAdd(&counts[bk], 1u);
    }

    float4 c = ((const float4*)emb)[bk * 16 + j];
    float dx = c.x - xj.x, dy = c.y - xj.y, dz = c.z - xj.z, dw = c.w - xj.w;
    float4 q;
    q.x = xj.x + dx; q.y = xj.y + dy;   // straight-through: x + (q - x)
    q.z = xj.z + dz; q.w = xj.w + dw;
    ((float4*)out)[t * 16 + j] = q;
    float local = dx * dx + dy * dy + dz * dz + dw * dw;

    double ld = (double)local;
#pragma unroll
    for (int off = 32; off > 0; off >>= 1) ld += __shfl_down(ld, off, 64);
    __shared__ double wsum[4];
    int lane = threadIdx.x & 63, wid = threadIdx.x >> 6;
    if (lane == 0) wsum[wid] = ld;
    __syncthreads();
    if (threadIdx.x == 0)
        blocksums[blockIdx.x] = (wsum[0] + wsum[1]) + (wsum[2] + wsum[3]);
}

__global__ __launch_bounds__(256) void vq_finalize(const unsigned* __restrict__ counts,
                                                   const double* __restrict__ blocksums,
                                                   float* __restrict__ out) {
    const int tid = threadIdx.x;
    double e = 0.0;
#pragma unroll
    for (int i = 0; i < 8; ++i) {
        int k = tid + i * 256;
        float p = (float)counts[k] / 65536.0f;
        out[PROB_OFF + k] = p;
        double pd = (double)p;
        e += pd * log(pd + 1e-5);
    }
    double s = 0.0;
#pragma unroll
    for (int i = 0; i < NBLK_EPI / 256; ++i) s += blocksums[tid + i * 256];
#pragma unroll
    for (int off = 32; off > 0; off >>= 1) {
        e += __shfl_down(e, off, 64);
        s += __shfl_down(s, off, 64);
    }
    __shared__ double we[4], ws2[4];
    int lane = tid & 63, wid = tid >> 6;
    if (lane == 0) { we[wid] = e; ws2[wid] = s; }
    __syncthreads();
    if (tid == 0) {
        double entropy = (we[0] + we[1]) + (we[2] + we[3]);
        double sumsq   = (ws2[0] + ws2[1]) + (ws2[2] + ws2[3]);
        double mse     = sumsq / (double)((size_t)N_TOK * D);
        out[SCAL_OFF + 0] = (float)(1.25 * mse + 0.1 * entropy); // vq_loss
        out[SCAL_OFF + 1] = (float)mse;                          // commitment_loss
        out[SCAL_OFF + 2] = (float)mse;                          // codebook_loss
        out[SCAL_OFF + 3] = (float)exp(-entropy);                // perplexity
        out[SCAL_OFF + 4] = (float)entropy;                      // entropy_loss
    }
}

extern "C" void kernel_launch(void* const* d_in, const int* in_sizes, int n_in,
                              void* d_out, int out_size, void* d_ws, size_t ws_size,
                              hipStream_t stream) {
    const float* x   = (const float*)d_in[0];
    const float* emb = (const float*)d_in[1];
    float* out = (float*)d_out;

    char* ws = (char*)d_ws;
    float*              hnorm     = (float*)(ws + WS_HNORM);
    unsigned*           counts    = (unsigned*)(ws + WS_COUNT);
    unsigned long long* kand      = (unsigned long long*)(ws + WS_KAND);
    double*             blocksums = (double*)(ws + WS_BSUM);
    _Float16*           ehi       = (_Float16*)(ws + WS_EHI);
    _Float16*           elo       = (_Float16*)(ws + WS_ELO);

    vq_init<<<K * 16 / 256, 256, 0, stream>>>(emb, hnorm, counts, blocksums, ehi, elo);
    vq_dist<<<SPLIT * (N_TOK / TOK_PER_BLK), 256, 0, stream>>>(x, hnorm, ehi, elo, kand);
    vq_epilogue<<<NBLK_EPI, 256, 0, stream>>>(x, emb, hnorm, kand, counts, blocksums, out);
    vq_finalize<<<1, 256, 0, stream>>>(counts, blocksums, out);
}

// Round 11
// 165.538 us; speedup vs baseline: 1.1658x; 1.1658x over previous
//
#include <hip/hip_runtime.h>
#include <float.h>

typedef _Float16 half8 __attribute__((ext_vector_type(8)));
typedef _Float16 half4 __attribute__((ext_vector_type(4)));
typedef float    f32x4 __attribute__((ext_vector_type(4)));

// Problem constants
constexpr int N_TOK = 65536;        // 16*64*64 tokens
constexpr int D     = 64;           // embedding dim
constexpr int K     = 2048;         // codebook size
constexpr int SPLIT = 8;            // code-range split (r8 best)
constexpr int KO    = K / SPLIT;    // 256 codes per split
constexpr int TILE_C = 32;          // codes per LDS tile (8.3 KB) (r8 best)
constexpr int TOK_PER_BLK = 256;    // 4 waves x 64 tokens (vq_dist)
constexpr int NBLK_EPI = N_TOK * 16 / 256;   // 4096 epilogue blocks
constexpr float EPS_RESCORE = 2e-3f; // >> pruner dist error (~1e-4 w/o ll term)

// Output layout (all float32, concatenated in reference return order)
constexpr size_t QN       = (size_t)N_TOK * D;
constexpr size_t SCAL_OFF = QN;
constexpr size_t IDX_OFF  = QN + 5;
constexpr size_t PROB_OFF = IDX_OFF + N_TOK;

// Workspace layout (bytes), total ~4.8 MB
constexpr size_t WS_HNORM = 0;                                    // [K] f32  0.5*||c||^2
constexpr size_t WS_COUNT = 8192;                                 // [K] u32
constexpr size_t WS_KAND  = 16384;                                // [N][SPLIT] u64 keys (4 MB)
constexpr size_t WS_BSUM  = WS_KAND + (size_t)N_TOK * SPLIT * 8;  // [4096] double
constexpr size_t WS_EHI   = WS_BSUM + (size_t)NBLK_EPI * 8;       // [K*D] f16
constexpr size_t WS_ELO   = WS_EHI + (size_t)K * D * 2;           // [K*D] f16

__device__ inline unsigned long long pack_key(float d, int k) {
    unsigned u = __float_as_uint(d);
    u = (u & 0x80000000u) ? ~u : (u | 0x80000000u);   // monotone float->uint
    return ((unsigned long long)u << 32) | (unsigned)k;
}

__device__ inline float unpack_dist(unsigned long long key) {
    unsigned u = (unsigned)(key >> 32);
    u = (u & 0x80000000u) ? (u & 0x7FFFFFFFu) : ~u;   // inverse monotone map
    return __uint_as_float(u);
}

__device__ inline unsigned long long shfl_xor_u64_w16(unsigned long long v, int m) {
    int lo = __shfl_xor((int)(unsigned)v, m, 16);
    int hi = __shfl_xor((int)(unsigned)(v >> 32), m, 16);
    return ((unsigned long long)(unsigned)hi << 32) | (unsigned)lo;
}

// 16 lanes per codebook row: coalesced convert + hnorm; zero counts/blocksums.
__global__ __launch_bounds__(256) void vq_init(const float* __restrict__ emb,
                                               float* __restrict__ hnorm,
                                               unsigned* __restrict__ counts,
                                               double* __restrict__ blocksums,
                                               _Float16* __restrict__ ehi,
                                               _Float16* __restrict__ elo) {
    int g = blockIdx.x * 256 + threadIdx.x;   // 0..32767
    int r = g >> 4;                           // codebook row
    int j = g & 15;                           // float4 within row
    float4 v = ((const float4*)emb)[r * 16 + j];
    float vv[4] = {v.x, v.y, v.z, v.w};
    half4 h, l;
#pragma unroll
    for (int i = 0; i < 4; ++i) {
        _Float16 hh = (_Float16)vv[i];
        h[i] = hh;
        l[i] = (_Float16)(vv[i] - (float)hh);
    }
    ((half4*)ehi)[r * 16 + j] = h;
    ((half4*)elo)[r * 16 + j] = l;

    float p = v.x * v.x + v.y * v.y + v.z * v.z + v.w * v.w;
#pragma unroll
    for (int off = 1; off < 16; off <<= 1) p += __shfl_xor(p, off, 16);
    if (j == 0) hnorm[r] = 0.5f * p;
    if (g < K) counts[g] = 0u;
    if (g < NBLK_EPI) blocksums[g] = 0.0;
}

// MFMA pruning pass, r8 base (SPLIT=8, TILE_C=32, swizzled LDS) + two changes:
// (1) 6-MFMA chain: hh + xh*cl + xl*ch; the ll term (~1e-6) is dropped --
//     covered by the EPS_RESCORE belt in the epilogue.
// (2) software pipeline: tile t+1's global values prefetched into registers
//     BEFORE tile t's compute, so global latency hides under the MFMA body;
//     barrier only fences the cheap LDS store.
__global__ __launch_bounds__(256) void vq_dist(const float* __restrict__ x,
                                               const float* __restrict__ hnorm,
                                               const _Float16* __restrict__ ehi,
                                               const _Float16* __restrict__ elo,
                                               unsigned long long* __restrict__ kand) {
    __shared__ _Float16 lds_hi[TILE_C * D];   // 4 KB
    __shared__ _Float16 lds_lo[TILE_C * D];   // 4 KB
    __shared__ float    lds_hn[TILE_C];

    const int tid  = threadIdx.x;
    const int lane = tid & 63;
    const int wav  = tid >> 6;
    const int s    = blockIdx.x >> 8;       // split-outer (0..7)
    const int tb   = blockIdx.x & 255;
    const int Tw   = tb * TOK_PER_BLK + wav * 64;
    const int m16  = lane & 15;             // A row (token) / B col (code)
    const int g    = lane >> 4;             // k-chunk group (0..3)
    const int ko   = g * 8;

    // A fragments: 4 a-tiles x 2 k-chunks, negated, hi/lo fp16 split
    half8 axh[4][2], axl[4][2];
#pragma unroll
    for (int a = 0; a < 4; ++a) {
        const float* xr = x + (size_t)(Tw + 16 * a + m16) * D;
#pragma unroll
        for (int c = 0; c < 2; ++c) {
            const float4* p4 = (const float4*)(xr + 32 * c + ko);
            float4 q0 = p4[0], q1 = p4[1];
            float v[8] = {q0.x, q0.y, q0.z, q0.w, q1.x, q1.y, q1.z, q1.w};
            half8 h, l;
#pragma unroll
            for (int j = 0; j < 8; ++j) {
                float nv = -v[j];
                _Float16 hh = (_Float16)nv;
                h[j] = hh;
                l[j] = (_Float16)(nv - (float)hh);
            }
            axh[a][c] = h; axl[a][c] = l;
        }
    }

    float best_d[4][4];
    int   best_k[4][4];
#pragma unroll
    for (int a = 0; a < 4; ++a)
#pragma unroll
        for (int r = 0; r < 4; ++r) { best_d[a][r] = FLT_MAX; best_k[a][r] = 0; }

    // staging indices: thread -> (code row sm, chunk sc); swizzled slot
    const int sm = tid >> 3;
    const int sc = tid & 7;
    const int sslot = (sc * TILE_C + (sm ^ sc)) * 8;
    const int kobase = s * KO;

    // prologue: tile 0 into registers
    half8 rhi = *(const half8*)(ehi + (size_t)(kobase + sm) * D + sc * 8);
    half8 rlo = *(const half8*)(elo + (size_t)(kobase + sm) * D + sc * 8);
    float rhn = (tid < TILE_C) ? hnorm[kobase + tid] : 0.f;

    for (int tile = 0; tile < KO / TILE_C; ++tile) {
        const int kbase = kobase + tile * TILE_C;
        __syncthreads();   // previous tile's readers done
        *(half8*)(lds_hi + sslot) = rhi;
        *(half8*)(lds_lo + sslot) = rlo;
        if (tid < TILE_C) lds_hn[tid] = rhn;
        __syncthreads();

        if (tile + 1 < KO / TILE_C) {      // prefetch next tile (in flight all compute)
            const int nb = kbase + TILE_C;
            rhi = *(const half8*)(ehi + (size_t)(nb + sm) * D + sc * 8);
            rlo = *(const half8*)(elo + (size_t)(nb + sm) * D + sc * 8);
            if (tid < TILE_C) rhn = hnorm[nb + tid];
        }

#pragma unroll
        for (int st = 0; st < 2; ++st) {
            const int cl = st * 16 + m16;
            const int s0 = (g * TILE_C + (cl ^ g)) * 8;
            const int s1 = ((4 + g) * TILE_C + (cl ^ (4 + g))) * 8;
            half8 bh0 = *(const half8*)(lds_hi + s0);
            half8 bh1 = *(const half8*)(lds_hi + s1);
            half8 bl0 = *(const half8*)(lds_lo + s0);
            half8 bl1 = *(const half8*)(lds_lo + s1);
            const float hn = lds_hn[cl];
            const int code = kbase + cl;
#pragma unroll
            for (int a = 0; a < 4; ++a) {
                f32x4 acc1 = {0.f, 0.f, 0.f, 0.f};   // hh terms (|.|~8)
                f32x4 acc2 = {0.f, 0.f, 0.f, 0.f};   // cross corrections (~2e-3)
                acc1 = __builtin_amdgcn_mfma_f32_16x16x32_f16(axh[a][0], bh0, acc1, 0, 0, 0);
                acc1 = __builtin_amdgcn_mfma_f32_16x16x32_f16(axh[a][1], bh1, acc1, 0, 0, 0);
                acc2 = __builtin_amdgcn_mfma_f32_16x16x32_f16(axl[a][0], bh0, acc2, 0, 0, 0);
                acc2 = __builtin_amdgcn_mfma_f32_16x16x32_f16(axl[a][1], bh1, acc2, 0, 0, 0);
                acc2 = __builtin_amdgcn_mfma_f32_16x16x32_f16(axh[a][0], bl0, acc2, 0, 0, 0);
                acc2 = __builtin_amdgcn_mfma_f32_16x16x32_f16(axh[a][1], bl1, acc2, 0, 0, 0);
                // ll term dropped: |sum xl*cl| ~1e-6 << EPS_RESCORE
#pragma unroll
                for (int r = 0; r < 4; ++r) {
                    float d = hn + (acc1[r] + acc2[r]);   // argmin-equiv dist
                    if (d < best_d[a][r]) { best_d[a][r] = d; best_k[a][r] = code; }
                }
            }
        }
    }

    // reduce over the 16 code-columns; u64 key min => smaller dist, tie -> smaller k
#pragma unroll
    for (int a = 0; a < 4; ++a)
#pragma unroll
        for (int r = 0; r < 4; ++r) {
            unsigned long long key = pack_key(best_d[a][r], best_k[a][r]);
#pragma unroll
            for (int off = 8; off; off >>= 1) {
                unsigned long long o = shfl_xor_u64_w16(key, off);
                if (o < key) key = o;
            }
            if (m16 == 0) {
                int token = Tw + 16 * a + g * 4 + r;
                kand[(size_t)token * SPLIT + s] = key;
            }
        }
}

// 16 lanes per token, everything coalesced. Lane j holds split j&7; the
// 8-lane xor group (off=1,2,4) covers each split exactly once -> kmin and
// cnt = #contender splits. cnt>1 -> exact fp32 rescore with coalesced
// 16-lane row reads + shfl-dot (ascending k, strict < = first occurrence).
__global__ __launch_bounds__(256) void vq_epilogue(const float* __restrict__ x,
                                                   const float* __restrict__ emb,
                                                   const float* __restrict__ hnorm,
                                                   const unsigned long long* __restrict__ kand,
                                                   unsigned* __restrict__ counts,
                                                   double* __restrict__ blocksums,
                                                   float* __restrict__ out) {
    const int gidx = blockIdx.x * 256 + threadIdx.x;
    const int t = gidx >> 4;
    const int j = gidx & 15;

    const unsigned long long mykey = kand[(size_t)t * SPLIT + (j & 7)];
    unsigned long long kmin = mykey;
#pragma unroll
    for (int off = 1; off < 8; off <<= 1) {   // 8-lane xor group = all 8 splits
        unsigned long long o = shfl_xor_u64_w16(kmin, off);
        if (o < kmin) kmin = o;
    }
    int bk = (int)(unsigned)(kmin & 0xFFFFFFFFu);
    const float fmin = unpack_dist(kmin);

    const float4 xj = ((const float4*)x)[t * 16 + j];

    // contender flags: each split appears exactly once in the 8-lane xor group
    const float dj = unpack_dist(mykey);
    int flag = (dj <= fmin + EPS_RESCORE) ? 1 : 0;
    int cnt = flag;
#pragma unroll
    for (int off = 1; off < 8; off <<= 1) cnt += __shfl_xor(cnt, off, 16);

    if (cnt > 1) {   // >1 contender split: exact fp32 rescore (group-uniform branch)
        float best = FLT_MAX;
#pragma unroll
        for (int s = 0; s < SPLIT; ++s) {    // ascending k across splits; lane s holds split s
            int fs = __shfl(flag, s, 16);
            int ks = __shfl((int)(unsigned)(mykey & 0xFFFFFFFFu), s, 16);
            if (fs) {
                float4 c = ((const float4*)emb)[ks * 16 + j];
                float p = c.x * xj.x + c.y * xj.y + c.z * xj.z + c.w * xj.w;
#pragma unroll
                for (int off = 1; off < 16; off <<= 1) p += __shfl_xor(p, off, 16);
                float hd = hnorm[ks] - p;
                if (hd < best) { best = hd; bk = ks; }
            }
        }
    }

    if (j == 0) {
        out[IDX_OFF + t] = (float)bk;
        atomicAdd(&counts[bk], 1u);
    }

    float4 c = ((const float4*)emb)[bk * 16 + j];
    float dx = c.x - xj.x, dy = c.y - xj.y, dz = c.z - xj.z, dw = c.w - xj.w;
    float4 q;
    q.x = xj.x + dx; q.y = xj.y + dy;   // straight-through: x + (q - x)
    q.z = xj.z + dz; q.w = xj.w + dw;
    ((float4*)out)[t * 16 + j] = q;
    float local = dx * dx + dy * dy + dz * dz + dw * dw;

    double ld = (double)local;
#pragma unroll
    for (int off = 32; off > 0; off >>= 1) ld += __shfl_down(ld, off, 64);
    __shared__ double wsum[4];
    int lane = threadIdx.x & 63, wid = threadIdx.x >> 6;
    if (lane == 0) wsum[wid] = ld;
    __syncthreads();
    if (threadIdx.x == 0)
        blocksums[blockIdx.x] = (wsum[0] + wsum[1]) + (wsum[2] + wsum[3]);
}

__global__ __launch_bounds__(256) void vq_finalize(const unsigned* __restrict__ counts,
                                                   const double* __restrict__ blocksums,
                                                   float* __restrict__ out) {
    const int tid = threadIdx.x;
    double e = 0.0;
#pragma unroll
    for (int i = 0; i < 8; ++i) {
        int k = tid + i * 256;
        float p = (float)counts[k] / 65536.0f;
        out[PROB_OFF + k] = p;
        double pd = (double)p;
        e += pd * log(pd + 1e-5);
    }
    double s = 0.0;
#pragma unroll
    for (int i = 0; i < NBLK_EPI / 256; ++i) s += blocksums[tid + i * 256];
#pragma unroll
    for (int off = 32; off > 0; off >>= 1) {
        e += __shfl_down(e, off, 64);
        s += __shfl_down(s, off, 64);
    }
    __shared__ double we[4], ws2[4];
    int lane = tid & 63, wid = tid >> 6;
    if (lane == 0) { we[wid] = e; ws2[wid] = s; }
    __syncthreads();
    if (tid == 0) {
        double entropy = (we[0] + we[1]) + (we[2] + we[3]);
        double sumsq   = (ws2[0] + ws2[1]) + (ws2[2] + ws2[3]);
        double mse     = sumsq / (double)((size_t)N_TOK * D);
        out[SCAL_OFF + 0] = (float)(1.25 * mse + 0.1 * entropy); // vq_loss
        out[SCAL_OFF + 1] = (float)mse;                          // commitment_loss
        out[SCAL_OFF + 2] = (float)mse;                          // codebook_loss
        out[SCAL_OFF + 3] = (float)exp(-entropy);                // perplexity
        out[SCAL_OFF + 4] = (float)entropy;                      // entropy_loss
    }
}

extern "C" void kernel_launch(void* const* d_in, const int* in_sizes, int n_in,
                              void* d_out, int out_size, void* d_ws, size_t ws_size,
                              hipStream_t stream) {
    const float* x   = (const float*)d_in[0];
    const float* emb = (const float*)d_in[1];
    float* out = (float*)d_out;

    char* ws = (char*)d_ws;
    float*              hnorm     = (float*)(ws + WS_HNORM);
    unsigned*           counts    = (unsigned*)(ws + WS_COUNT);
    unsigned long long* kand      = (unsigned long long*)(ws + WS_KAND);
    double*             blocksums = (double*)(ws + WS_BSUM);
    _Float16*           ehi       = (_Float16*)(ws + WS_EHI);
    _Float16*           elo       = (_Float16*)(ws + WS_ELO);

    vq_init<<<K * 16 / 256, 256, 0, stream>>>(emb, hnorm, counts, blocksums, ehi, elo);
    vq_dist<<<SPLIT * (N_TOK / TOK_PER_BLK), 256, 0, stream>>>(x, hnorm, ehi, elo, kand);
    vq_epilogue<<<NBLK_EPI, 256, 0, stream>>>(x, emb, hnorm, kand, counts, blocksums, out);
    vq_finalize<<<1, 256, 0, stream>>>(counts, blocksums, out);
}

// Round 12
// 164.719 us; speedup vs baseline: 1.1716x; 1.0050x over previous
//
#include <hip/hip_runtime.h>
#include <float.h>

typedef _Float16 half8 __attribute__((ext_vector_type(8)));
typedef _Float16 half4 __attribute__((ext_vector_type(4)));
typedef float    f32x4 __attribute__((ext_vector_type(4)));

// Problem constants
constexpr int N_TOK = 65536;        // 16*64*64 tokens
constexpr int D     = 64;           // embedding dim
constexpr int K     = 2048;         // codebook size
constexpr int NRANGE = 8;           // 8 ascending code ranges (= r11 SPLIT)
constexpr int KO    = K / NRANGE;   // 256 codes per range
constexpr int TOK_PER_BLK = 64;     // tokens per fused block (4 waves, same tokens)
constexpr int NBLK = N_TOK / TOK_PER_BLK;    // 1024 fused blocks
constexpr float EPS_RESCORE = 2e-3f; // >> pruner dist error (~1e-4 w/o ll term)

// Output layout (all float32, concatenated in reference return order)
constexpr size_t QN       = (size_t)N_TOK * D;
constexpr size_t SCAL_OFF = QN;
constexpr size_t IDX_OFF  = QN + 5;
constexpr size_t PROB_OFF = IDX_OFF + N_TOK;

// Workspace layout (bytes), total ~550 KB (kand eliminated)
constexpr size_t WS_HNORM = 0;                          // [K] f32  0.5*||c||^2
constexpr size_t WS_COUNT = 8192;                       // [K] u32
constexpr size_t WS_BSUM  = 16384;                      // [1024] double
constexpr size_t WS_EHI   = WS_BSUM + (size_t)NBLK * 8; // [K*D] f16
constexpr size_t WS_ELO   = WS_EHI + (size_t)K * D * 2; // [K*D] f16

__device__ inline unsigned long long pack_key(float d, int k) {
    unsigned u = __float_as_uint(d);
    u = (u & 0x80000000u) ? ~u : (u | 0x80000000u);   // monotone float->uint
    return ((unsigned long long)u << 32) | (unsigned)k;
}

__device__ inline float unpack_dist(unsigned long long key) {
    unsigned u = (unsigned)(key >> 32);
    u = (u & 0x80000000u) ? (u & 0x7FFFFFFFu) : ~u;   // inverse monotone map
    return __uint_as_float(u);
}

__device__ inline unsigned long long shfl_xor_u64_w16(unsigned long long v, int m) {
    int lo = __shfl_xor((int)(unsigned)v, m, 16);
    int hi = __shfl_xor((int)(unsigned)(v >> 32), m, 16);
    return ((unsigned long long)(unsigned)hi << 32) | (unsigned)lo;
}

// 16 lanes per codebook row: coalesced convert + hnorm; zero counts/blocksums.
__global__ __launch_bounds__(256) void vq_init(const float* __restrict__ emb,
                                               float* __restrict__ hnorm,
                                               unsigned* __restrict__ counts,
                                               double* __restrict__ blocksums,
                                               _Float16* __restrict__ ehi,
                                               _Float16* __restrict__ elo) {
    int g = blockIdx.x * 256 + threadIdx.x;   // 0..32767
    int r = g >> 4;                           // codebook row
    int j = g & 15;                           // float4 within row
    float4 v = ((const float4*)emb)[r * 16 + j];
    float vv[4] = {v.x, v.y, v.z, v.w};
    half4 h, l;
#pragma unroll
    for (int i = 0; i < 4; ++i) {
        _Float16 hh = (_Float16)vv[i];
        h[i] = hh;
        l[i] = (_Float16)(vv[i] - (float)hh);
    }
    ((half4*)ehi)[r * 16 + j] = h;
    ((half4*)elo)[r * 16 + j] = l;

    float p = v.x * v.x + v.y * v.y + v.z * v.z + v.w * v.w;
#pragma unroll
    for (int off = 1; off < 16; off <<= 1) p += __shfl_xor(p, off, 16);
    if (j == 0) hnorm[r] = 0.5f * p;
    if (g < K) counts[g] = 0u;
    if (g < NBLK) blocksums[g] = 0.0;
}

// Fused kernel: one block = 64 tokens x ALL 2048 codes.
// Wave w scans ranges s=2w and 2w+1 (ascending k; bit-identical MFMA chains
// to r11's per-split pass: 6-MFMA acc1/acc2, hn at end). Per-(token,range)
// u64 keys meet in LDS; merge + EPS-belt + exact fp32 rescore + quantize/
// hist/sumsq all inline while x/codebook are hot. No kand, x read once.
__global__ __launch_bounds__(256) void vq_fused(const float* __restrict__ x,
                                                const float* __restrict__ emb,
                                                const float* __restrict__ hnorm,
                                                const _Float16* __restrict__ ehi,
                                                const _Float16* __restrict__ elo,
                                                unsigned* __restrict__ counts,
                                                double* __restrict__ blocksums,
                                                float* __restrict__ out) {
    __shared__ unsigned long long kls[64][NRANGE + 1];   // +1 pad: bank-spread
    __shared__ int bks[64];
    __shared__ double wsum[4];

    const int tid  = threadIdx.x;
    const int lane = tid & 63;
    const int wav  = tid >> 6;
    const int t0   = blockIdx.x * TOK_PER_BLK;
    const int m16  = lane & 15;             // A row (token) / B col (code)
    const int g    = lane >> 4;             // k-chunk group (0..3)
    const int ko   = g * 8;

    // A fragments: 4 a-tiles (16 tokens each = the block's 64), negated hi/lo
    half8 axh[4][2], axl[4][2];
#pragma unroll
    for (int a = 0; a < 4; ++a) {
        const float* xr = x + (size_t)(t0 + 16 * a + m16) * D;
#pragma unroll
        for (int c = 0; c < 2; ++c) {
            const float4* p4 = (const float4*)(xr + 32 * c + ko);
            float4 q0 = p4[0], q1 = p4[1];
            float v[8] = {q0.x, q0.y, q0.z, q0.w, q1.x, q1.y, q1.z, q1.w};
            half8 h, l;
#pragma unroll
            for (int j = 0; j < 8; ++j) {
                float nv = -v[j];
                _Float16 hh = (_Float16)nv;
                h[j] = hh;
                l[j] = (_Float16)(nv - (float)hh);
            }
            axh[a][c] = h; axl[a][c] = l;
        }
    }

    for (int phase = 0; phase < 2; ++phase) {
        const int s = wav * 2 + phase;      // range index, ascending k
        const int kobase = s * KO;

        float best_d[4][4];
        int   best_k[4][4];
#pragma unroll
        for (int a = 0; a < 4; ++a)
#pragma unroll
            for (int r = 0; r < 4; ++r) { best_d[a][r] = FLT_MAX; best_k[a][r] = 0; }

        // register double-buffer of this lane's B fragments (r6-proven)
        int code = kobase + m16;
        const _Float16* er = ehi + (size_t)code * D;
        const _Float16* el = elo + (size_t)code * D;
        half8 bh0 = *(const half8*)(er + ko);
        half8 bh1 = *(const half8*)(er + 32 + ko);
        half8 bl0 = *(const half8*)(el + ko);
        half8 bl1 = *(const half8*)(el + 32 + ko);
        float hn  = hnorm[code];

        for (int tile = 0; tile < KO / 16; ++tile) {
            const half8 cbh0 = bh0, cbh1 = bh1, cbl0 = bl0, cbl1 = bl1;
            const float chn = hn;
            const int ccode = code;
            if (tile + 1 < KO / 16) {       // prefetch next 16-code step
                code += 16;
                const _Float16* ner = ehi + (size_t)code * D;
                const _Float16* nel = elo + (size_t)code * D;
                bh0 = *(const half8*)(ner + ko);
                bh1 = *(const half8*)(ner + 32 + ko);
                bl0 = *(const half8*)(nel + ko);
                bl1 = *(const half8*)(nel + 32 + ko);
                hn  = hnorm[code];
            }
#pragma unroll
            for (int a = 0; a < 4; ++a) {
                f32x4 acc1 = {0.f, 0.f, 0.f, 0.f};   // hh terms (|.|~8)
                f32x4 acc2 = {0.f, 0.f, 0.f, 0.f};   // cross corrections (~2e-3)
                acc1 = __builtin_amdgcn_mfma_f32_16x16x32_f16(axh[a][0], cbh0, acc1, 0, 0, 0);
                acc1 = __builtin_amdgcn_mfma_f32_16x16x32_f16(axh[a][1], cbh1, acc1, 0, 0, 0);
                acc2 = __builtin_amdgcn_mfma_f32_16x16x32_f16(axl[a][0], cbh0, acc2, 0, 0, 0);
                acc2 = __builtin_amdgcn_mfma_f32_16x16x32_f16(axl[a][1], cbh1, acc2, 0, 0, 0);
                acc2 = __builtin_amdgcn_mfma_f32_16x16x32_f16(axh[a][0], cbl0, acc2, 0, 0, 0);
                acc2 = __builtin_amdgcn_mfma_f32_16x16x32_f16(axh[a][1], cbl1, acc2, 0, 0, 0);
                // ll term dropped: |sum xl*cl| ~1e-6 << EPS_RESCORE
#pragma unroll
                for (int r = 0; r < 4; ++r) {
                    float d = chn + (acc1[r] + acc2[r]);   // argmin-equiv dist
                    if (d < best_d[a][r]) { best_d[a][r] = d; best_k[a][r] = ccode; }
                }
            }
        }

        // col-reduce over 16 codes; u64 min => smaller dist, tie -> smaller k
#pragma unroll
        for (int a = 0; a < 4; ++a)
#pragma unroll
            for (int r = 0; r < 4; ++r) {
                unsigned long long key = pack_key(best_d[a][r], best_k[a][r]);
#pragma unroll
                for (int off = 8; off; off >>= 1) {
                    unsigned long long o = shfl_xor_u64_w16(key, off);
                    if (o < key) key = o;
                }
                if (m16 == 0) kls[16 * a + g * 4 + r][s] = key;  // wave-private columns
            }
    }
    __syncthreads();

    // merge the 8 range-winners per token (wave 0, one lane per token)
    if (tid < 64) {
        float ds[NRANGE]; int kk[NRANGE];
        unsigned long long kmin = ~0ULL;
#pragma unroll
        for (int s = 0; s < NRANGE; ++s) {
            unsigned long long key = kls[tid][s];
            ds[s] = unpack_dist(key);
            kk[s] = (int)(unsigned)(key & 0xFFFFFFFFu);
            if (key < kmin) kmin = key;
        }
        int bk = (int)(unsigned)(kmin & 0xFFFFFFFFu);
        const float fmin = unpack_dist(kmin);
        int cnt = 0;
#pragma unroll
        for (int s = 0; s < NRANGE; ++s) cnt += (ds[s] <= fmin + EPS_RESCORE) ? 1 : 0;

        if (cnt > 1) {   // rare near-tie: exact fp32 rescore, ascending k, strict <
            float best = FLT_MAX;
            const float* xr = x + (size_t)(t0 + tid) * D;
            for (int s = 0; s < NRANGE; ++s) {
                if (ds[s] <= fmin + EPS_RESCORE) {
                    const int k = kk[s];
                    const float* cr = emb + (size_t)k * D;
                    float s0 = 0.f, s1 = 0.f, s2 = 0.f, s3 = 0.f;
#pragma unroll
                    for (int i = 0; i < 16; ++i) {
                        s0 = fmaf(cr[4 * i + 0], xr[4 * i + 0], s0);
                        s1 = fmaf(cr[4 * i + 1], xr[4 * i + 1], s1);
                        s2 = fmaf(cr[4 * i + 2], xr[4 * i + 2], s2);
                        s3 = fmaf(cr[4 * i + 3], xr[4 * i + 3], s3);
                    }
                    float hd = hnorm[k] - ((s0 + s1) + (s2 + s3));
                    if (hd < best) { best = hd; bk = k; }
                }
            }
        }
        bks[tid] = bk;
        out[IDX_OFF + t0 + tid] = (float)bk;
        atomicAdd(&counts[bk], 1u);
    }
    __syncthreads();

    // inline epilogue: quantize + sumsq (4 threads per token, coalesced)
    const int tok = tid >> 2;
    const int i4  = tid & 3;
    const int bk  = bks[tok];
    const float4* xr4 = (const float4*)(x + (size_t)(t0 + tok) * D);
    const float4* cr4 = (const float4*)(emb + (size_t)bk * D);
    float4* qr4 = (float4*)(out + (size_t)(t0 + tok) * D);
    float local = 0.f;
#pragma unroll
    for (int ii = 0; ii < 4; ++ii) {
        const int idx = i4 + 4 * ii;
        float4 xv = xr4[idx];
        float4 cv = cr4[idx];
        float dx = cv.x - xv.x, dy = cv.y - xv.y;
        float dz = cv.z - xv.z, dw = cv.w - xv.w;
        local += dx * dx + dy * dy + dz * dz + dw * dw;
        float4 q;
        q.x = xv.x + dx; q.y = xv.y + dy;   // straight-through: x + (q - x)
        q.z = xv.z + dz; q.w = xv.w + dw;
        qr4[idx] = q;
    }
    double ld = (double)local;
#pragma unroll
    for (int off = 32; off > 0; off >>= 1) ld += __shfl_down(ld, off, 64);
    if (lane == 0) wsum[wav] = ld;
    __syncthreads();
    if (tid == 0)
        blocksums[blockIdx.x] = (wsum[0] + wsum[1]) + (wsum[2] + wsum[3]);
}

__global__ __launch_bounds__(256) void vq_finalize(const unsigned* __restrict__ counts,
                                                   const double* __restrict__ blocksums,
                                                   float* __restrict__ out) {
    const int tid = threadIdx.x;
    double e = 0.0;
#pragma unroll
    for (int i = 0; i < 8; ++i) {
        int k = tid + i * 256;
        float p = (float)counts[k] / 65536.0f;
        out[PROB_OFF + k] = p;
        double pd = (double)p;
        e += pd * log(pd + 1e-5);
    }
    double s = 0.0;
#pragma unroll
    for (int i = 0; i < NBLK / 256; ++i) s += blocksums[tid + i * 256];
#pragma unroll
    for (int off = 32; off > 0; off >>= 1) {
        e += __shfl_down(e, off, 64);
        s += __shfl_down(s, off, 64);
    }
    __shared__ double we[4], ws2[4];
    int lane = tid & 63, wid = tid >> 6;
    if (lane == 0) { we[wid] = e; ws2[wid] = s; }
    __syncthreads();
    if (tid == 0) {
        double entropy = (we[0] + we[1]) + (we[2] + we[3]);
        double sumsq   = (ws2[0] + ws2[1]) + (ws2[2] + ws2[3]);
        double mse     = sumsq / (double)((size_t)N_TOK * D);
        out[SCAL_OFF + 0] = (float)(1.25 * mse + 0.1 * entropy); // vq_loss
        out[SCAL_OFF + 1] = (float)mse;                          // commitment_loss
        out[SCAL_OFF + 2] = (float)mse;                          // codebook_loss
        out[SCAL_OFF + 3] = (float)exp(-entropy);                // perplexity
        out[SCAL_OFF + 4] = (float)entropy;                      // entropy_loss
    }
}

extern "C" void kernel_launch(void* const* d_in, const int* in_sizes, int n_in,
                              void* d_out, int out_size, void* d_ws, size_t ws_size,
                              hipStream_t stream) {
    const float* x   = (const float*)d_in[0];
    const float* emb = (const float*)d_in[1];
    float* out = (float*)d_out;

    char* ws = (char*)d_ws;
    float*    hnorm     = (float*)(ws + WS_HNORM);
    unsigned* counts    = (unsigned*)(ws + WS_COUNT);
    double*   blocksums = (double*)(ws + WS_BSUM);
    _Float16* ehi       = (_Float16*)(ws + WS_EHI);
    _Float16* elo       = (_Float16*)(ws + WS_ELO);

    vq_init<<<K * 16 / 256, 256, 0, stream>>>(emb, hnorm, counts, blocksums, ehi, elo);
    vq_fused<<<NBLK, 256, 0, stream>>>(x, emb, hnorm, ehi, elo, counts, blocksums, out);
    vq_finalize<<<1, 256, 0, stream>>>(counts, blocksums, out);
}

// Round 13
// 157.649 us; speedup vs baseline: 1.2242x; 1.0448x over previous
//
#include <hip/hip_runtime.h>
#include <float.h>

typedef _Float16 half8 __attribute__((ext_vector_type(8)));
typedef float    f32x4 __attribute__((ext_vector_type(4)));

// Problem constants
constexpr int N_TOK = 65536;        // 16*64*64 tokens
constexpr int D     = 64;           // embedding dim
constexpr int K     = 2048;         // codebook size
constexpr int TILE_C = 64;          // codes per staged tile (16 KB hi+lo)
constexpr int NTILE  = K / TILE_C;  // 32
constexpr int TOK_PER_BLK = 64;     // tokens per fused block
constexpr int NBLK = N_TOK / TOK_PER_BLK;    // 1024 fused blocks
constexpr float EPS_RESCORE = 2e-3f; // >> pruner dist error (~1e-4)

// Output layout (all float32, concatenated in reference return order)
constexpr size_t QN       = (size_t)N_TOK * D;
constexpr size_t SCAL_OFF = QN;
constexpr size_t IDX_OFF  = QN + 5;
constexpr size_t PROB_OFF = IDX_OFF + N_TOK;

// Workspace layout (bytes), total ~537 KB
constexpr size_t WS_HNORM = 0;                          // [K] f32  0.5*||c||^2
constexpr size_t WS_COUNT = 8192;                       // [K] u32
constexpr size_t WS_BSUM  = 16384;                      // [1024] double
constexpr size_t WS_SW    = 24576;                      // [NTILE][16][64] half8 pre-swizzled

__device__ inline unsigned long long pack_key(float d, int k) {
    unsigned u = __float_as_uint(d);
    u = (u & 0x80000000u) ? ~u : (u | 0x80000000u);   // monotone float->uint
    return ((unsigned long long)u << 32) | (unsigned)k;
}

__device__ inline float unpack_dist(unsigned long long key) {
    unsigned u = (unsigned)(key >> 32);
    u = (u & 0x80000000u) ? (u & 0x7FFFFFFFu) : ~u;   // inverse monotone map
    return __uint_as_float(u);
}

__device__ inline unsigned long long shfl_xor_u64_w16(unsigned long long v, int m) {
    int lo = __shfl_xor((int)(unsigned)v, m, 16);
    int hi = __shfl_xor((int)(unsigned)(v >> 32), m, 16);
    return ((unsigned long long)(unsigned)hi << 32) | (unsigned)lo;
}

// async global->LDS, 16 B per lane, dest = lds_base + lane*16
__device__ inline void load16_to_lds(const void* g, void* l) {
    __builtin_amdgcn_global_load_lds(
        (const __attribute__((address_space(1))) void*)g,
        (__attribute__((address_space(3))) void*)l, 16, 0, 0);
}

// One thread per (code row r, 8-elem chunk c0): writes the PRE-SWIZZLED hi/lo
// codebook image. sw[tile][jj][lane] (half8): jj<8 = hi chunk jj, jj>=8 = lo
// chunk jj-8; lane = (r&63) ^ (jj&7)  -> global_load_lds with lane-contiguous
// dest reproduces the conflict-free swizzled LDS layout directly.
__global__ __launch_bounds__(256) void vq_init(const float* __restrict__ emb,
                                               float* __restrict__ hnorm,
                                               unsigned* __restrict__ counts,
                                               double* __restrict__ blocksums,
                                               half8* __restrict__ sw) {
    const int g  = blockIdx.x * 256 + threadIdx.x;   // 0..16383
    const int r  = g >> 3;                           // code row
    const int c0 = g & 7;                            // chunk within row
    const float4* p4 = (const float4*)(emb + (size_t)r * D + 8 * c0);
    float4 q0 = p4[0], q1 = p4[1];
    float v[8] = {q0.x, q0.y, q0.z, q0.w, q1.x, q1.y, q1.z, q1.w};
    half8 h, l;
    float s = 0.f;
#pragma unroll
    for (int i = 0; i < 8; ++i) {
        s += v[i] * v[i];
        _Float16 hh = (_Float16)v[i];
        h[i] = hh;
        l[i] = (_Float16)(v[i] - (float)hh);
    }
    const int tile = r >> 6;
    const int lane = (r & 63) ^ c0;
    sw[((size_t)tile * 16 + c0) * 64 + lane]     = h;   // hi chunk c0
    sw[((size_t)tile * 16 + 8 + c0) * 64 + lane] = l;   // lo chunk c0

#pragma unroll
    for (int off = 1; off < 8; off <<= 1) s += __shfl_xor(s, off, 8);
    if (c0 == 0) hnorm[r] = 0.5f * s;
    if (g < K) counts[g] = 0u;
    if (g < NBLK) blocksums[g] = 0.0;
}

// Fused: one block = 64 tokens x ALL 2048 codes. 32 tiles of 64 codes,
// double-buffered LDS staged via async global_load_lds from the pre-swizzled
// image (no staging VGPRs/ds_writes). The 4 waves split each tile's codes
// 4-ways (per-wave ascending subsets). 6-MFMA chain (acc1 hh, acc2 cross;
// hn added at end -- proven err ~4e-5). Merge 4 candidates via EPS belt +
// exact fp32 rescore (packed-key min = first occurrence), inline epilogue.
__global__ __launch_bounds__(256) void vq_fused(const float* __restrict__ x,
                                                const float* __restrict__ emb,
                                                const float* __restrict__ hnorm,
                                                const half8* __restrict__ sw,
                                                unsigned* __restrict__ counts,
                                                double* __restrict__ blocksums,
                                                float* __restrict__ out) {
    __shared__ half8 buf[2][16 * 64];                 // 2 x 16 KB
    __shared__ unsigned long long kls[64][5];         // 4 candidates + pad
    __shared__ int bks[64];
    __shared__ double wsum[4];

    const int tid  = threadIdx.x;
    const int lane = tid & 63;
    const int wav  = tid >> 6;
    const int t0   = blockIdx.x * TOK_PER_BLK;
    const int m16  = lane & 15;             // A row (token) / B col (code)
    const int g    = lane >> 4;             // k-chunk group (0..3)
    const int ko   = g * 8;

    // A fragments: 4 a-tiles (the block's 64 tokens), negated hi/lo fp16 split
    half8 axh[4][2], axl[4][2];
#pragma unroll
    for (int a = 0; a < 4; ++a) {
        const float* xr = x + (size_t)(t0 + 16 * a + m16) * D;
#pragma unroll
        for (int c = 0; c < 2; ++c) {
            const float4* p4 = (const float4*)(xr + 32 * c + ko);
            float4 q0 = p4[0], q1 = p4[1];
            float v[8] = {q0.x, q0.y, q0.z, q0.w, q1.x, q1.y, q1.z, q1.w};
            half8 h, l;
#pragma unroll
            for (int j = 0; j < 8; ++j) {
                float nv = -v[j];
                _Float16 hh = (_Float16)nv;
                h[j] = hh;
                l[j] = (_Float16)(nv - (float)hh);
            }
            axh[a][c] = h; axl[a][c] = l;
        }
    }

    float best_d[4][4];
    int   best_k[4][4];
#pragma unroll
    for (int a = 0; a < 4; ++a)
#pragma unroll
        for (int r = 0; r < 4; ++r) { best_d[a][r] = FLT_MAX; best_k[a][r] = 0; }

    // this lane's code-in-tile and conflict-free LDS slots (tile-invariant)
    const int cit = wav * 16 + m16;         // wave w owns codes [w*16, w*16+16)
    const int s_bh0 = g * 64        + (cit ^ g);
    const int s_bh1 = (g + 4) * 64  + (cit ^ (g + 4));
    const int s_bl0 = (8 + g) * 64  + (cit ^ g);
    const int s_bl1 = (12 + g) * 64 + (cit ^ (g + 4));

    // prologue: stage tile 0 into buf[0] (wave wav issues chunks 4w..4w+3)
#pragma unroll
    for (int i = 0; i < 4; ++i) {
        const int q = wav * 4 + i;
        load16_to_lds(sw + (size_t)q * 64 + lane, &buf[0][q * 64]);
    }
    __syncthreads();   // compiler drains vmcnt before s_barrier -> buf0 ready

    for (int t = 0; t < NTILE; ++t) {
        const int cur = t & 1;
        if (t + 1 < NTILE) {                // async prefetch next tile
            const half8* src = sw + ((size_t)(t + 1) * 16) * 64;
#pragma unroll
            for (int i = 0; i < 4; ++i) {
                const int q = wav * 4 + i;
                load16_to_lds(src + (size_t)q * 64 + lane, &buf[cur ^ 1][q * 64]);
            }
        }

        const int code = t * TILE_C + cit;
        const float hn = hnorm[code];
        half8 bh0 = buf[cur][s_bh0];
        half8 bh1 = buf[cur][s_bh1];
        half8 bl0 = buf[cur][s_bl0];
        half8 bl1 = buf[cur][s_bl1];
#pragma unroll
        for (int a = 0; a < 4; ++a) {
            f32x4 acc1 = {0.f, 0.f, 0.f, 0.f};   // hh terms (|.|~8)
            f32x4 acc2 = {0.f, 0.f, 0.f, 0.f};   // cross corrections (~2e-3)
            acc1 = __builtin_amdgcn_mfma_f32_16x16x32_f16(axh[a][0], bh0, acc1, 0, 0, 0);
            acc1 = __builtin_amdgcn_mfma_f32_16x16x32_f16(axh[a][1], bh1, acc1, 0, 0, 0);
            acc2 = __builtin_amdgcn_mfma_f32_16x16x32_f16(axl[a][0], bh0, acc2, 0, 0, 0);
            acc2 = __builtin_amdgcn_mfma_f32_16x16x32_f16(axl[a][1], bh1, acc2, 0, 0, 0);
            acc2 = __builtin_amdgcn_mfma_f32_16x16x32_f16(axh[a][0], bl0, acc2, 0, 0, 0);
            acc2 = __builtin_amdgcn_mfma_f32_16x16x32_f16(axh[a][1], bl1, acc2, 0, 0, 0);
            // ll term dropped: |sum xl*cl| ~1e-6 << EPS_RESCORE
#pragma unroll
            for (int r = 0; r < 4; ++r) {
                float d = hn + (acc1[r] + acc2[r]);   // argmin-equiv dist
                if (d < best_d[a][r]) { best_d[a][r] = d; best_k[a][r] = code; }
            }
        }
        __syncthreads();   // readers of cur done; next buf's loads drained
    }

    // col-reduce over this wave's 16 code-columns; write wave candidate
#pragma unroll
    for (int a = 0; a < 4; ++a)
#pragma unroll
        for (int r = 0; r < 4; ++r) {
            unsigned long long key = pack_key(best_d[a][r], best_k[a][r]);
#pragma unroll
            for (int off = 8; off; off >>= 1) {
                unsigned long long o = shfl_xor_u64_w16(key, off);
                if (o < key) key = o;
            }
            if (m16 == 0) kls[16 * a + g * 4 + r][wav] = key;
        }
    __syncthreads();

    // merge the 4 wave-winners per token (wave 0, one lane per token)
    if (tid < 64) {
        float ds[4]; int kk[4];
        unsigned long long kmin = ~0ULL;
#pragma unroll
        for (int w = 0; w < 4; ++w) {
            unsigned long long key = kls[tid][w];
            ds[w] = unpack_dist(key);
            kk[w] = (int)(unsigned)(key & 0xFFFFFFFFu);
            if (key < kmin) kmin = key;
        }
        int bk = (int)(unsigned)(kmin & 0xFFFFFFFFu);
        const float fmin = unpack_dist(kmin);
        int cnt = 0;
#pragma unroll
        for (int w = 0; w < 4; ++w) cnt += (ds[w] <= fmin + EPS_RESCORE) ? 1 : 0;

        if (cnt > 1) {   // rare near-tie: exact fp32 rescore; packed-key min
            unsigned long long bkey = ~0ULL;   // = smaller dist, tie smaller k
            const float* xr = x + (size_t)(t0 + tid) * D;
            for (int w = 0; w < 4; ++w) {
                if (ds[w] <= fmin + EPS_RESCORE) {
                    const int k = kk[w];
                    const float* cr = emb + (size_t)k * D;
                    float s0 = 0.f, s1 = 0.f, s2 = 0.f, s3 = 0.f;
#pragma unroll
                    for (int i = 0; i < 16; ++i) {
                        s0 = fmaf(cr[4 * i + 0], xr[4 * i + 0], s0);
                        s1 = fmaf(cr[4 * i + 1], xr[4 * i + 1], s1);
                        s2 = fmaf(cr[4 * i + 2], xr[4 * i + 2], s2);
                        s3 = fmaf(cr[4 * i + 3], xr[4 * i + 3], s3);
                    }
                    float hd = hnorm[k] - ((s0 + s1) + (s2 + s3));
                    unsigned long long key = pack_key(hd, k);
                    if (key < bkey) bkey = key;
                }
            }
            bk = (int)(unsigned)(bkey & 0xFFFFFFFFu);
        }
        bks[tid] = bk;
        out[IDX_OFF + t0 + tid] = (float)bk;
        atomicAdd(&counts[bk], 1u);
    }
    __syncthreads();

    // inline epilogue: quantize + sumsq (4 threads per token, coalesced)
    const int tok = tid >> 2;
    const int i4  = tid & 3;
    const int bk  = bks[tok];
    const float4* xr4 = (const float4*)(x + (size_t)(t0 + tok) * D);
    const float4* cr4 = (const float4*)(emb + (size_t)bk * D);
    float4* qr4 = (float4*)(out + (size_t)(t0 + tok) * D);
    float local = 0.f;
#pragma unroll
    for (int ii = 0; ii < 4; ++ii) {
        const int idx = i4 + 4 * ii;
        float4 xv = xr4[idx];
        float4 cv = cr4[idx];
        float dx = cv.x - xv.x, dy = cv.y - xv.y;
        float dz = cv.z - xv.z, dw = cv.w - xv.w;
        local += dx * dx + dy * dy + dz * dz + dw * dw;
        float4 q;
        q.x = xv.x + dx; q.y = xv.y + dy;   // straight-through: x + (q - x)
        q.z = xv.z + dz; q.w = xv.w + dw;
        qr4[idx] = q;
    }
    double ld = (double)local;
#pragma unroll
    for (int off = 32; off > 0; off >>= 1) ld += __shfl_down(ld, off, 64);
    if (lane == 0) wsum[wav] = ld;
    __syncthreads();
    if (tid == 0)
        blocksums[blockIdx.x] = (wsum[0] + wsum[1]) + (wsum[2] + wsum[3]);
}

__global__ __launch_bounds__(256) void vq_finalize(const unsigned* __restrict__ counts,
                                                   const double* __restrict__ blocksums,
                                                   float* __restrict__ out) {
    const int tid = threadIdx.x;
    double e = 0.0;
#pragma unroll
    for (int i = 0; i < 8; ++i) {
        int k = tid + i * 256;
        float p = (float)counts[k] / 65536.0f;
        out[PROB_OFF + k] = p;
        double pd = (double)p;
        e += pd * log(pd + 1e-5);
    }
    double s = 0.0;
#pragma unroll
    for (int i = 0; i < NBLK / 256; ++i) s += blocksums[tid + i * 256];
#pragma unroll
    for (int off = 32; off > 0; off >>= 1) {
        e += __shfl_down(e, off, 64);
        s += __shfl_down(s, off, 64);
    }
    __shared__ double we[4], ws2[4];
    int lane = tid & 63, wid = tid >> 6;
    if (lane == 0) { we[wid] = e; ws2[wid] = s; }
    __syncthreads();
    if (tid == 0) {
        double entropy = (we[0] + we[1]) + (we[2] + we[3]);
        double sumsq   = (ws2[0] + ws2[1]) + (ws2[2] + ws2[3]);
        double mse     = sumsq / (double)((size_t)N_TOK * D);
        out[SCAL_OFF + 0] = (float)(1.25 * mse + 0.1 * entropy); // vq_loss
        out[SCAL_OFF + 1] = (float)mse;                          // commitment_loss
        out[SCAL_OFF + 2] = (float)mse;                          // codebook_loss
        out[SCAL_OFF + 3] = (float)exp(-entropy);                // perplexity
        out[SCAL_OFF + 4] = (float)entropy;                      // entropy_loss
    }
}

extern "C" void kernel_launch(void* const* d_in, const int* in_sizes, int n_in,
                              void* d_out, int out_size, void* d_ws, size_t ws_size,
                              hipStream_t stream) {
    const float* x   = (const float*)d_in[0];
    const float* emb = (const float*)d_in[1];
    float* out = (float*)d_out;

    char* ws = (char*)d_ws;
    float*    hnorm     = (float*)(ws + WS_HNORM);
    unsigned* counts    = (unsigned*)(ws + WS_COUNT);
    double*   blocksums = (double*)(ws + WS_BSUM);
    half8*    sw        = (half8*)(ws + WS_SW);

    vq_init<<<K * 8 / 256, 256, 0, stream>>>(emb, hnorm, counts, blocksums, sw);
    vq_fused<<<NBLK, 256, 0, stream>>>(x, emb, hnorm, sw, counts, blocksums, out);
    vq_finalize<<<1, 256, 0, stream>>>(counts, blocksums, out);
}